// Round 6
// baseline (2759.483 us; speedup 1.0000x reference)
//
#include <hip/hip_runtime.h>
#include <float.h>
#include <stdint.h>

#define QN 8
#define KN 1024
#define DN 64
// split-fp16 scan error bound ~1.5e-3 + register drift ~1e-5; margin 4x headroom
#define MARGIN 6.0e-3f

typedef float    f32x16 __attribute__((ext_vector_type(16)));
typedef _Float16 f16x8  __attribute__((ext_vector_type(8)));

union AB8 { uint4 v; uint32_t u[4]; f16x8 h; };

// ===================== FROZEN reference-emulation machinery =====================
__device__ __forceinline__ float np_sumsq64(const float* a) {
    float p[DN];
    #pragma unroll
    for (int t = 0; t < DN; ++t) p[t] = __fmul_rn(a[t], a[t]);
    float l1[32];
    #pragma unroll
    for (int t = 0; t < 32; ++t) l1[t] = __fadd_rn(p[t], p[t + 32]);
    float l2[16];
    #pragma unroll
    for (int t = 0; t < 16; ++t) l2[t] = __fadd_rn(l1[t], l1[t + 16]);
    float l3[8];
    #pragma unroll
    for (int t = 0; t < 8; ++t) l3[t] = __fadd_rn(l2[t], l2[t + 8]);
    float l4[4];
    #pragma unroll
    for (int t = 0; t < 4; ++t) l4[t] = __fadd_rn(l3[t], l3[t + 4]);
    const float l5a = __fadd_rn(l4[0], l4[2]);
    const float l5b = __fadd_rn(l4[1], l4[3]);
    return __fadd_rn(l5a, l5b);
}

// ---- Low-footprint PASS A: frozen rr. Pairs (t, t+32) rebuilt together; l1/l2/l3/l4
// tree op-identical to the validated rr_tree. Residual per element: qd = sequential
// fadd chain over l<J, rex = fsub(x, qd) — bit-identical to build_rex values. ----
template<int J>
__device__ __forceinline__ float rr_twopass(const float* __restrict__ xrow,
                                            const float* __restrict__ cb,
                                            const int* cs) {
    float l1[32];
    #pragma unroll
    for (int t4 = 0; t4 < 8; ++t4) {
        const float4 xa = *(const float4*)(xrow + 4 * t4);
        const float4 xb = *(const float4*)(xrow + 4 * t4 + 32);
        float qa0 = 0.f, qa1 = 0.f, qa2 = 0.f, qa3 = 0.f;
        float qb0 = 0.f, qb1 = 0.f, qb2 = 0.f, qb3 = 0.f;
        #pragma unroll
        for (int l = 0; l < J; ++l) {
            const float* row = cb + ((size_t)l * KN + cs[l]) * DN;
            const float4 fa = *(const float4*)(row + 4 * t4);
            const float4 fb = *(const float4*)(row + 4 * t4 + 32);
            qa0 = __fadd_rn(qa0, fa.x); qa1 = __fadd_rn(qa1, fa.y);
            qa2 = __fadd_rn(qa2, fa.z); qa3 = __fadd_rn(qa3, fa.w);
            qb0 = __fadd_rn(qb0, fb.x); qb1 = __fadd_rn(qb1, fb.y);
            qb2 = __fadd_rn(qb2, fb.z); qb3 = __fadd_rn(qb3, fb.w);
        }
        const float ra0 = __fsub_rn(xa.x, qa0), ra1 = __fsub_rn(xa.y, qa1);
        const float ra2 = __fsub_rn(xa.z, qa2), ra3 = __fsub_rn(xa.w, qa3);
        const float rb0 = __fsub_rn(xb.x, qb0), rb1 = __fsub_rn(xb.y, qb1);
        const float rb2 = __fsub_rn(xb.z, qb2), rb3 = __fsub_rn(xb.w, qb3);
        l1[4*t4+0] = __fadd_rn(__fmul_rn(ra0, ra0), __fmul_rn(rb0, rb0));
        l1[4*t4+1] = __fadd_rn(__fmul_rn(ra1, ra1), __fmul_rn(rb1, rb1));
        l1[4*t4+2] = __fadd_rn(__fmul_rn(ra2, ra2), __fmul_rn(rb2, rb2));
        l1[4*t4+3] = __fadd_rn(__fmul_rn(ra3, ra3), __fmul_rn(rb3, rb3));
    }
    float l2[16];
    #pragma unroll
    for (int t = 0; t < 16; ++t) l2[t] = __fadd_rn(l1[t], l1[t + 16]);
    float l3[8];
    #pragma unroll
    for (int t = 0; t < 8; ++t) l3[t] = __fadd_rn(l2[t], l2[t + 8]);
    float l4[4];
    #pragma unroll
    for (int t = 0; t < 4; ++t) l4[t] = __fadd_rn(l3[t], l3[t + 4]);
    return __fadd_rn(__fadd_rn(l4[0], l4[2]), __fadd_rn(l4[1], l4[3]));
}

// ---- Low-footprint 2-candidate exact rescore (INLINE, no ABI call). PASS B rebuilds
// rex ascending-d (bit-identical values) and runs the frozen sequential cr chains. ----
template<int J>
__device__ __forceinline__ int rescore2_lp(const float* __restrict__ xrow,
                                           const float* __restrict__ cb,
                                           const float* __restrict__ cnj,
                                           const int* cs, int i1, int i2) {
    const float rr = rr_twopass<J>(xrow, cb, cs);

    const float* cbj = cb + (size_t)J * KN * DN;
    const float* c0p = cbj + (size_t)i1 * DN;
    const float* c1p = cbj + (size_t)i2 * DN;
    float cr0 = 0.f, cr1 = 0.f;
    #pragma unroll
    for (int d4 = 0; d4 < DN / 4; ++d4) {
        const float4 xv = *(const float4*)(xrow + 4 * d4);
        float q0 = 0.f, q1 = 0.f, q2 = 0.f, q3 = 0.f;
        #pragma unroll
        for (int l = 0; l < J; ++l) {
            const float4 cv = *(const float4*)(
                cb + ((size_t)l * KN + cs[l]) * DN + 4 * d4);
            q0 = __fadd_rn(q0, cv.x); q1 = __fadd_rn(q1, cv.y);
            q2 = __fadd_rn(q2, cv.z); q3 = __fadd_rn(q3, cv.w);
        }
        const float r0 = __fsub_rn(xv.x, q0), r1 = __fsub_rn(xv.y, q1);
        const float r2 = __fsub_rn(xv.z, q2), r3 = __fsub_rn(xv.w, q3);
        const float4 a = *(const float4*)(c0p + 4 * d4);
        const float4 b = *(const float4*)(c1p + 4 * d4);
        cr0 = __fmaf_rn(r0, a.x, cr0); cr1 = __fmaf_rn(r0, b.x, cr1);
        cr0 = __fmaf_rn(r1, a.y, cr0); cr1 = __fmaf_rn(r1, b.y, cr1);
        cr0 = __fmaf_rn(r2, a.z, cr0); cr1 = __fmaf_rn(r2, b.z, cr1);
        cr0 = __fmaf_rn(r3, a.w, cr0); cr1 = __fmaf_rn(r3, b.w, cr1);
    }
    const float d2c0 = __fadd_rn(__fsub_rn(rr, __fmul_rn(2.0f, cr0)), cnj[i1]);
    const float d2c1 = __fadd_rn(__fsub_rn(rr, __fmul_rn(2.0f, cr1)), cnj[i2]);

    float bd = d2c0; int bk = i1;
    if (d2c1 < bd || (d2c1 == bd && i2 < bk)) { bd = d2c1; bk = i2; }
    return bk;
}

// Inline dispatcher; after the stage loop unrolls, the switch const-folds per call site.
__device__ __forceinline__ int rescore2_sw(int j, const float* __restrict__ xrow,
                                           const float* __restrict__ cb,
                                           const float* __restrict__ cnj,
                                           int c0, int c1, int c2, int c3,
                                           int c4, int c5, int c6, int c7,
                                           int i1, int i2) {
    int cs[QN] = {c0, c1, c2, c3, c4, c5, c6, c7};
    switch (j) {
#define R2_CASE(J) case J: return rescore2_lp<J>(xrow, cb, cnj, cs, i1, i2);
        R2_CASE(0) R2_CASE(1) R2_CASE(2) R2_CASE(3)
        R2_CASE(4) R2_CASE(5) R2_CASE(6) R2_CASE(7)
#undef R2_CASE
    }
    return i1;
}

// Reference-exact residual rebuild, J compile-time (for the deep path).
template<int J>
__device__ __forceinline__ void build_rex(const float* __restrict__ xrow,
                                          const float* __restrict__ cb,
                                          const int* cs, float rex[DN]) {
    #pragma unroll
    for (int d4 = 0; d4 < DN / 4; ++d4) {
        const float4 xv = *(const float4*)(xrow + 4 * d4);
        float q0 = 0.f, q1 = 0.f, q2 = 0.f, q3 = 0.f;
        #pragma unroll
        for (int l = 0; l < J; ++l) {
            const float4 cv = *(const float4*)(
                cb + ((size_t)l * KN + cs[l]) * DN + 4 * d4);
            q0 = __fadd_rn(q0, cv.x); q1 = __fadd_rn(q1, cv.y);
            q2 = __fadd_rn(q2, cv.z); q3 = __fadd_rn(q3, cv.w);
        }
        rex[4*d4+0] = __fsub_rn(xv.x, q0); rex[4*d4+1] = __fsub_rn(xv.y, q1);
        rex[4*d4+2] = __fsub_rn(xv.z, q2); rex[4*d4+3] = __fsub_rn(xv.w, q3);
    }
}

__device__ __forceinline__ float rr_tree(const float rex[DN]) {
    float l1[32];
    #pragma unroll
    for (int t = 0; t < 32; ++t)
        l1[t] = __fadd_rn(__fmul_rn(rex[t], rex[t]), __fmul_rn(rex[t+32], rex[t+32]));
    float l2[16];
    #pragma unroll
    for (int t = 0; t < 16; ++t) l2[t] = __fadd_rn(l1[t], l1[t + 16]);
    float l3[8];
    #pragma unroll
    for (int t = 0; t < 8; ++t) l3[t] = __fadd_rn(l2[t], l2[t + 8]);
    float l4[4];
    #pragma unroll
    for (int t = 0; t < 4; ++t) l4[t] = __fadd_rn(l3[t], l3[t + 4]);
    return __fadd_rn(__fadd_rn(l4[0], l4[2]), __fadd_rn(l4[1], l4[3]));
}

// Full reference-exact scan (deep tie path), k-unrolled x4, ascending-k compare fold.
template<int J>
__device__ __forceinline__ int full_exact_t(const float* __restrict__ xrow,
                                            const float* __restrict__ cb,
                                            const float* __restrict__ cnj,
                                            const int* cs) {
    float rex[DN];
    build_rex<J>(xrow, cb, cs, rex);
    const float rr = rr_tree(rex);

    const float* cbj = cb + (size_t)J * KN * DN;
    float bd = FLT_MAX; int bk = 0;
    #pragma unroll 1
    for (int k = 0; k < KN; k += 4) {
        float cr0 = 0.f, cr1 = 0.f, cr2 = 0.f, cr3 = 0.f;
        const float* p0 = cbj + (size_t)(k + 0) * DN;
        const float* p1 = cbj + (size_t)(k + 1) * DN;
        const float* p2 = cbj + (size_t)(k + 2) * DN;
        const float* p3 = cbj + (size_t)(k + 3) * DN;
        #pragma unroll
        for (int d4 = 0; d4 < DN / 4; ++d4) {
            const float4 a = *(const float4*)(p0 + 4 * d4);
            const float4 b = *(const float4*)(p1 + 4 * d4);
            const float4 c = *(const float4*)(p2 + 4 * d4);
            const float4 e = *(const float4*)(p3 + 4 * d4);
            const float r0 = rex[4*d4+0], r1 = rex[4*d4+1];
            const float r2 = rex[4*d4+2], r3 = rex[4*d4+3];
            cr0 = __fmaf_rn(r0, a.x, cr0); cr0 = __fmaf_rn(r1, a.y, cr0);
            cr0 = __fmaf_rn(r2, a.z, cr0); cr0 = __fmaf_rn(r3, a.w, cr0);
            cr1 = __fmaf_rn(r0, b.x, cr1); cr1 = __fmaf_rn(r1, b.y, cr1);
            cr1 = __fmaf_rn(r2, b.z, cr1); cr1 = __fmaf_rn(r3, b.w, cr1);
            cr2 = __fmaf_rn(r0, c.x, cr2); cr2 = __fmaf_rn(r1, c.y, cr2);
            cr2 = __fmaf_rn(r2, c.z, cr2); cr2 = __fmaf_rn(r3, c.w, cr2);
            cr3 = __fmaf_rn(r0, e.x, cr3); cr3 = __fmaf_rn(r1, e.y, cr3);
            cr3 = __fmaf_rn(r2, e.z, cr3); cr3 = __fmaf_rn(r3, e.w, cr3);
        }
        const float d20 = __fadd_rn(__fsub_rn(rr, __fmul_rn(2.0f, cr0)), cnj[k + 0]);
        const float d21 = __fadd_rn(__fsub_rn(rr, __fmul_rn(2.0f, cr1)), cnj[k + 1]);
        const float d22 = __fadd_rn(__fsub_rn(rr, __fmul_rn(2.0f, cr2)), cnj[k + 2]);
        const float d23 = __fadd_rn(__fsub_rn(rr, __fmul_rn(2.0f, cr3)), cnj[k + 3]);
        if (d20 < bd) { bd = d20; bk = k + 0; }
        if (d21 < bd) { bd = d21; bk = k + 1; }
        if (d22 < bd) { bd = d22; bk = k + 2; }
        if (d23 < bd) { bd = d23; bk = k + 3; }
    }
    return bk;
}

// Deep path stays a real call (rare at wave level); scalar args, no struct-by-value.
__device__ __attribute__((noinline)) int full_exact_call(
    int j, const float* __restrict__ xrow, const float* __restrict__ cb,
    const float* __restrict__ cnj,
    int c0, int c1, int c2, int c3, int c4, int c5, int c6, int c7) {
    int cs[QN] = {c0, c1, c2, c3, c4, c5, c6, c7};
    switch (j) {
#define FE_CASE(J) case J: return full_exact_t<J>(xrow, cb, cnj, cs);
        FE_CASE(0) FE_CASE(1) FE_CASE(2) FE_CASE(3)
        FE_CASE(4) FE_CASE(5) FE_CASE(6) FE_CASE(7)
#undef FE_CASE
    }
    return 0;
}
// ===============================================================================

// ---------- Phase A: exact ||c||^2 + split-fp16(-2c) codebook in fragment order ----------
__global__ __launch_bounds__(256) void rvq_prep_kernel(const float* __restrict__ cb,
                                                       uint32_t* __restrict__ apackH,
                                                       uint32_t* __restrict__ apackL,
                                                       float* __restrict__ cn) {
    const int cidx = (int)blockIdx.x * 256 + (int)threadIdx.x;
    if (cidx >= QN * KN) return;
    float row[DN];
    const float4* cp = (const float4*)(cb + (size_t)cidx * DN);
    #pragma unroll
    for (int d4 = 0; d4 < DN / 4; ++d4) {
        const float4 v = cp[d4];
        row[4*d4+0] = v.x; row[4*d4+1] = v.y; row[4*d4+2] = v.z; row[4*d4+3] = v.w;
    }
    cn[cidx] = np_sumsq64(row);                       // frozen exact ||c||^2

    const int j = cidx >> 10, local = cidx & 1023;
    const int c = local >> 5, col = local & 31;
    #pragma unroll
    for (int kk = 0; kk < 4; ++kk) {
        #pragma unroll
        for (int hh = 0; hh < 2; ++hh) {
            AB8 uh, ul;
            #pragma unroll
            for (int e = 0; e < 8; ++e) {
                const float v = -2.0f * row[kk * 16 + hh * 8 + e];   // exact (x2, negate)
                const _Float16 hi = (_Float16)v;
                const float hr = (float)hi;
                const _Float16 lo = (_Float16)__fsub_rn(v, hr);
                uh.h[e] = hi; ul.h[e] = lo;
            }
            const size_t off = (((size_t)(j * 32 + c) * 4 + kk) * 256
                                + (((hh << 5) | col) << 2));
            *(uint4*)(apackH + off) = uh.v;
            *(uint4*)(apackL + off) = ul.v;
        }
    }
}

// med3-based top-3 insert (validated r2-r5).
#define INSV(sv, ixv, B1v, I1v, B2v, I2v, B3v) do {                          \
    const bool lt1 = (sv) < B1v, lt2 = (sv) < B2v;                           \
    B3v = __builtin_amdgcn_fmed3f((sv), B2v, B3v);                           \
    B2v = __builtin_amdgcn_fmed3f((sv), B1v, B2v);                           \
    I2v = lt1 ? I1v : (lt2 ? (ixv) : I2v);                                   \
    B1v = fminf((sv), B1v);                                                  \
    I1v = lt1 ? (ixv) : I1v;                                                 \
} while (0)

// split-fp16 pack/unpack helpers
__device__ __forceinline__ void splitpack2(float a, float b, uint32_t& H, uint32_t& L) {
    const _Float16 ah = (_Float16)a; const float ar = (float)ah;
    const _Float16 al = (_Float16)__fsub_rn(a, ar);
    const _Float16 bh = (_Float16)b; const float br = (float)bh;
    const _Float16 bl = (_Float16)__fsub_rn(b, br);
    H = (uint32_t)__builtin_bit_cast(uint16_t, ah)
      | ((uint32_t)__builtin_bit_cast(uint16_t, bh) << 16);
    L = (uint32_t)__builtin_bit_cast(uint16_t, al)
      | ((uint32_t)__builtin_bit_cast(uint16_t, bl) << 16);
}
__device__ __forceinline__ float up_lo(uint32_t u) {
    return (float)__builtin_bit_cast(_Float16, (uint16_t)(u & 0xFFFFu));
}
__device__ __forceinline__ float up_hi(uint32_t u) {
    return (float)__builtin_bit_cast(_Float16, (uint16_t)(u >> 16));
}

// ---------- Main: register-resident drifted residual, split-fp16 MFMA scan ----------
// 1 column group per wave (r5 structure). Rescue: common case INLINED low-footprint
// (no ABI call -> no wave-level spill storms); deep 3-way tie stays a rare call.
__global__ __launch_bounds__(256, 4) void rvq_encode_kernel(
    const float* __restrict__ x, const float* __restrict__ cb,
    const uint32_t* __restrict__ apackH, const uint32_t* __restrict__ apackL,
    const float* __restrict__ cnref,
    float* __restrict__ out_enc, float* __restrict__ out_q, int n) {
    const int tid  = (int)threadIdx.x;
    const int lane = tid & 63;
    const int wid  = tid >> 6;
    const int h    = lane >> 5;          // K-half this lane supplies
    const int iv   = (int)blockIdx.x * 128 + wid * 32 + (lane & 31);
    const int ivs  = iv < n ? iv : (n - 1);
    const float* xrow = x + (size_t)ivs * DN;

    // own-half drifted residual, split-packed: slot kk*4+t <-> dims kk*16+8h+2t, +1
    uint32_t rH[16], rL[16];
    #pragma unroll
    for (int kk = 0; kk < 4; ++kk) {
        const float4 a = *(const float4*)(xrow + kk * 16 + 8 * h);
        const float4 b = *(const float4*)(xrow + kk * 16 + 8 * h + 4);
        splitpack2(a.x, a.y, rH[kk*4+0], rL[kk*4+0]);
        splitpack2(a.z, a.w, rH[kk*4+1], rL[kk*4+1]);
        splitpack2(b.x, b.y, rH[kk*4+2], rL[kk*4+2]);
        splitpack2(b.z, b.w, rH[kk*4+3], rL[kk*4+3]);
    }

    int codes[QN] = {0, 0, 0, 0, 0, 0, 0, 0};

    #pragma unroll
    for (int j = 0; j < QN; ++j) {
        float b1 = FLT_MAX, b2 = FLT_MAX, b3 = FLT_MAX; int i1 = 0, i2 = 0;

        const uint32_t* aH  = apackH + (size_t)j * 32768;
        const uint32_t* aL  = apackL + (size_t)j * 32768;
        const float*    cnj = cnref + (size_t)j * KN;

        #pragma unroll 1
        for (int ch = 0; ch < 32; ++ch) {
            // acc init = exact fp32 cn (r3-validated); loads issue alongside A-frags
            f32x16 acc;
            #pragma unroll
            for (int q = 0; q < 4; ++q) {
                const float4 t = *(const float4*)(cnj + ch * 32 + q * 8 + h * 4);
                acc[4*q+0] = t.x; acc[4*q+1] = t.y; acc[4*q+2] = t.z; acc[4*q+3] = t.w;
            }
            #pragma unroll
            for (int kk = 0; kk < 4; ++kk) {
                AB8 ah_, al_, bh_, bl_;
                ah_.v = *(const uint4*)(aH + (size_t)(ch * 4 + kk) * 256 + lane * 4);
                al_.v = *(const uint4*)(aL + (size_t)(ch * 4 + kk) * 256 + lane * 4);
                bh_.u[0] = rH[kk*4+0]; bh_.u[1] = rH[kk*4+1];
                bh_.u[2] = rH[kk*4+2]; bh_.u[3] = rH[kk*4+3];
                bl_.u[0] = rL[kk*4+0]; bl_.u[1] = rL[kk*4+1];
                bl_.u[2] = rL[kk*4+2]; bl_.u[3] = rL[kk*4+3];
                acc = __builtin_amdgcn_mfma_f32_32x32x16_f16(ah_.h, bh_.h, acc, 0, 0, 0);
                acc = __builtin_amdgcn_mfma_f32_32x32x16_f16(al_.h, bh_.h, acc, 0, 0, 0);
                acc = __builtin_amdgcn_mfma_f32_32x32x16_f16(ah_.h, bl_.h, acc, 0, 0, 0);
            }
            const int ibase = ch * 32 + 4 * h;
            #pragma unroll
            for (int q = 0; q < 16; ++q) {
                const int ix = ibase + (q & 3) + 8 * (q >> 2);
                const float s = acc[q];
                INSV(s, ix, b1, i1, b2, i2, b3);
            }
        }

        // merge K-half partial lists (lanes l <-> l^32); pb3 can't reach I2 (strict <)
        {
            const float pb1 = __shfl_xor(b1, 32, 64); const int pi1 = __shfl_xor(i1, 32, 64);
            const float pb2 = __shfl_xor(b2, 32, 64); const int pi2 = __shfl_xor(i2, 32, 64);
            const float pb3 = __shfl_xor(b3, 32, 64);
            INSV(pb1, pi1, b1, i1, b2, i2, b3);
            INSV(pb2, pi2, b1, i1, b2, i2, b3);
            INSV(pb3, 0,   b1, i1, b2, i2, b3);
        }

        int chosen = i1;
        if (__builtin_expect(b2 - b1 < MARGIN, 0)) {
            if (__builtin_expect(b3 - b1 < MARGIN, 0)) {
                chosen = full_exact_call(j, xrow, cb, cnj,
                                         codes[0], codes[1], codes[2], codes[3],
                                         codes[4], codes[5], codes[6], codes[7]);
            } else {
                chosen = rescore2_sw(j, xrow, cb, cnj,
                                     codes[0], codes[1], codes[2], codes[3],
                                     codes[4], codes[5], codes[6], codes[7], i1, i2);
            }
        }
        codes[j] = chosen;   // j static (unrolled stage loop)

        // drift update on own half (scan-only precision; margin covers ~1e-5 drift)
        {
            const float* cw = cb + ((size_t)j * KN + chosen) * DN;
            #pragma unroll
            for (int kk = 0; kk < 4; ++kk) {
                const float4 a = *(const float4*)(cw + kk * 16 + 8 * h);
                const float4 b = *(const float4*)(cw + kk * 16 + 8 * h + 4);
                {
                    const float fa = __fadd_rn(up_lo(rH[kk*4+0]), up_lo(rL[kk*4+0]));
                    const float fb = __fadd_rn(up_hi(rH[kk*4+0]), up_hi(rL[kk*4+0]));
                    splitpack2(__fsub_rn(fa, a.x), __fsub_rn(fb, a.y), rH[kk*4+0], rL[kk*4+0]);
                }
                {
                    const float fa = __fadd_rn(up_lo(rH[kk*4+1]), up_lo(rL[kk*4+1]));
                    const float fb = __fadd_rn(up_hi(rH[kk*4+1]), up_hi(rL[kk*4+1]));
                    splitpack2(__fsub_rn(fa, a.z), __fsub_rn(fb, a.w), rH[kk*4+1], rL[kk*4+1]);
                }
                {
                    const float fa = __fadd_rn(up_lo(rH[kk*4+2]), up_lo(rL[kk*4+2]));
                    const float fb = __fadd_rn(up_hi(rH[kk*4+2]), up_hi(rL[kk*4+2]));
                    splitpack2(__fsub_rn(fa, b.x), __fsub_rn(fb, b.y), rH[kk*4+2], rL[kk*4+2]);
                }
                {
                    const float fa = __fadd_rn(up_lo(rH[kk*4+3]), up_lo(rL[kk*4+3]));
                    const float fb = __fadd_rn(up_hi(rH[kk*4+3]), up_hi(rL[kk*4+3]));
                    splitpack2(__fsub_rn(fa, b.z), __fsub_rn(fb, b.w), rH[kk*4+3], rL[kk*4+3]);
                }
            }
        }
    }

    if (h == 0 && iv < n) {
        // ---- encoded indices, packed write ----
        float4 e0, e1;
        e0.x = (float)codes[0]; e0.y = (float)codes[1];
        e0.z = (float)codes[2]; e0.w = (float)codes[3];
        e1.x = (float)codes[4]; e1.y = (float)codes[5];
        e1.z = (float)codes[6]; e1.w = (float)codes[7];
        *(float4*)(out_enc + (size_t)iv * QN)     = e0;
        *(float4*)(out_enc + (size_t)iv * QN + 4) = e1;

        // ---- quantized output: reference-exact q rebuilt from codes (frozen) ----
        float4* qo = (float4*)(out_q + (size_t)iv * DN);
        #pragma unroll 1
        for (int d4 = 0; d4 < DN / 4; ++d4) {
            float q0 = 0.f, q1 = 0.f, q2 = 0.f, q3 = 0.f;
            #pragma unroll
            for (int l = 0; l < QN; ++l) {
                const float4 v = *(const float4*)(
                    cb + ((size_t)l * KN + codes[l]) * DN + 4 * d4);
                q0 = __fadd_rn(q0, v.x); q1 = __fadd_rn(q1, v.y);
                q2 = __fadd_rn(q2, v.z); q3 = __fadd_rn(q3, v.w);
            }
            float4 o; o.x = q0; o.y = q1; o.z = q2; o.w = q3;
            qo[d4] = o;
        }
    }
}

extern "C" void kernel_launch(void* const* d_in, const int* in_sizes, int n_in,
                              void* d_out, int out_size, void* d_ws, size_t ws_size,
                              hipStream_t stream) {
    const float* x   = (const float*)d_in[0];
    const float* cbp = (const float*)d_in[1];
    const int n = in_sizes[0] / DN;

    float* out_enc = (float*)d_out;                   // [N, Q]
    float* out_q   = (float*)d_out + (size_t)n * QN;  // [N, D]

    // workspace: 1 MiB apackH + 1 MiB apackL (fragment-order fp16) + 32 KiB ||c||^2
    uint32_t* apackH = (uint32_t*)d_ws;
    uint32_t* apackL = (uint32_t*)((char*)d_ws + (size_t)QN * KN * DN * 2);
    float*    cn     = (float*)((char*)d_ws + (size_t)QN * KN * DN * 4);

    rvq_prep_kernel<<<dim3((QN * KN + 255) / 256), dim3(256), 0, stream>>>(
        cbp, apackH, apackL, cn);
    rvq_encode_kernel<<<dim3((n + 127) / 128), dim3(256), 0, stream>>>(
        x, cbp, apackH, apackL, cn, out_enc, out_q, n);
}

// Round 7
// 1328.585 us; speedup vs baseline: 2.0770x; 2.0770x over previous
//
#include <hip/hip_runtime.h>
#include <float.h>
#include <stdint.h>

#define QN 8
#define KN 1024
#define DN 64
// exact-register residual: scan error = split-fp16 truncation + MFMA fp32 accum
// (worst-case ~2.5e-4, no drift term). Margin 6x that.
#define MARGIN 1.5e-3f

typedef float    f32x16 __attribute__((ext_vector_type(16)));
typedef _Float16 f16x8  __attribute__((ext_vector_type(8)));

union AB8 { uint4 v; uint32_t u[4]; f16x8 h; };

// ===================== FROZEN reference-emulation machinery =====================
__device__ __forceinline__ float np_sumsq64(const float* a) {
    float p[DN];
    #pragma unroll
    for (int t = 0; t < DN; ++t) p[t] = __fmul_rn(a[t], a[t]);
    float l1[32];
    #pragma unroll
    for (int t = 0; t < 32; ++t) l1[t] = __fadd_rn(p[t], p[t + 32]);
    float l2[16];
    #pragma unroll
    for (int t = 0; t < 16; ++t) l2[t] = __fadd_rn(l1[t], l1[t + 16]);
    float l3[8];
    #pragma unroll
    for (int t = 0; t < 8; ++t) l3[t] = __fadd_rn(l2[t], l2[t + 8]);
    float l4[4];
    #pragma unroll
    for (int t = 0; t < 4; ++t) l4[t] = __fadd_rn(l3[t], l3[t + 4]);
    const float l5a = __fadd_rn(l4[0], l4[2]);
    const float l5b = __fadd_rn(l4[1], l4[3]);
    return __fadd_rn(l5a, l5b);
}

// Frozen rr butterfly tree over a full 64-dim residual (identical op sequence).
__device__ __forceinline__ float rr_tree(const float rex[DN]) {
    float l1[32];
    #pragma unroll
    for (int t = 0; t < 32; ++t)
        l1[t] = __fadd_rn(__fmul_rn(rex[t], rex[t]), __fmul_rn(rex[t+32], rex[t+32]));
    float l2[16];
    #pragma unroll
    for (int t = 0; t < 16; ++t) l2[t] = __fadd_rn(l1[t], l1[t + 16]);
    float l3[8];
    #pragma unroll
    for (int t = 0; t < 8; ++t) l3[t] = __fadd_rn(l2[t], l2[t + 8]);
    float l4[4];
    #pragma unroll
    for (int t = 0; t < 4; ++t) l4[t] = __fadd_rn(l3[t], l3[t + 4]);
    return __fadd_rn(__fadd_rn(l4[0], l4[2]), __fadd_rn(l4[1], l4[3]));
}

// Deep path: full reference-exact 1024-code scan, SINGLE instantiation (runtime j,
// predicated static unroll: fadd applied only when l<j -> bit-exact skip; loads are
// always in-bounds since codes[l>=j] == 0). Ascending-k compare fold = exact argmin.
__device__ __attribute__((noinline)) int full_exact_call(
    int j, const float* __restrict__ xrow, const float* __restrict__ cb,
    const float* __restrict__ cnj,
    int c0, int c1, int c2, int c3, int c4, int c5, int c6, int c7) {
    int cs[QN] = {c0, c1, c2, c3, c4, c5, c6, c7};
    float rex[DN];
    #pragma unroll
    for (int d4 = 0; d4 < DN / 4; ++d4) {
        const float4 xv = *(const float4*)(xrow + 4 * d4);
        float q0 = 0.f, q1 = 0.f, q2 = 0.f, q3 = 0.f;
        #pragma unroll
        for (int l = 0; l < QN; ++l) {
            const float4 cv = *(const float4*)(
                cb + ((size_t)l * KN + cs[l]) * DN + 4 * d4);
            const bool p = (l < j);
            q0 = p ? __fadd_rn(q0, cv.x) : q0;
            q1 = p ? __fadd_rn(q1, cv.y) : q1;
            q2 = p ? __fadd_rn(q2, cv.z) : q2;
            q3 = p ? __fadd_rn(q3, cv.w) : q3;
        }
        rex[4*d4+0] = __fsub_rn(xv.x, q0); rex[4*d4+1] = __fsub_rn(xv.y, q1);
        rex[4*d4+2] = __fsub_rn(xv.z, q2); rex[4*d4+3] = __fsub_rn(xv.w, q3);
    }
    const float rr = rr_tree(rex);

    const float* cbj = cb + (size_t)j * KN * DN;
    float bd = FLT_MAX; int bk = 0;
    #pragma unroll 1
    for (int k = 0; k < KN; k += 4) {
        float cr0 = 0.f, cr1 = 0.f, cr2 = 0.f, cr3 = 0.f;
        const float* p0 = cbj + (size_t)(k + 0) * DN;
        const float* p1 = cbj + (size_t)(k + 1) * DN;
        const float* p2 = cbj + (size_t)(k + 2) * DN;
        const float* p3 = cbj + (size_t)(k + 3) * DN;
        #pragma unroll
        for (int d4 = 0; d4 < DN / 4; ++d4) {
            const float4 a = *(const float4*)(p0 + 4 * d4);
            const float4 b = *(const float4*)(p1 + 4 * d4);
            const float4 c = *(const float4*)(p2 + 4 * d4);
            const float4 e = *(const float4*)(p3 + 4 * d4);
            const float r0 = rex[4*d4+0], r1 = rex[4*d4+1];
            const float r2 = rex[4*d4+2], r3 = rex[4*d4+3];
            cr0 = __fmaf_rn(r0, a.x, cr0); cr0 = __fmaf_rn(r1, a.y, cr0);
            cr0 = __fmaf_rn(r2, a.z, cr0); cr0 = __fmaf_rn(r3, a.w, cr0);
            cr1 = __fmaf_rn(r0, b.x, cr1); cr1 = __fmaf_rn(r1, b.y, cr1);
            cr1 = __fmaf_rn(r2, b.z, cr1); cr1 = __fmaf_rn(r3, b.w, cr1);
            cr2 = __fmaf_rn(r0, c.x, cr2); cr2 = __fmaf_rn(r1, c.y, cr2);
            cr2 = __fmaf_rn(r2, c.z, cr2); cr2 = __fmaf_rn(r3, c.w, cr2);
            cr3 = __fmaf_rn(r0, e.x, cr3); cr3 = __fmaf_rn(r1, e.y, cr3);
            cr3 = __fmaf_rn(r2, e.z, cr3); cr3 = __fmaf_rn(r3, e.w, cr3);
        }
        const float d20 = __fadd_rn(__fsub_rn(rr, __fmul_rn(2.0f, cr0)), cnj[k + 0]);
        const float d21 = __fadd_rn(__fsub_rn(rr, __fmul_rn(2.0f, cr1)), cnj[k + 1]);
        const float d22 = __fadd_rn(__fsub_rn(rr, __fmul_rn(2.0f, cr2)), cnj[k + 2]);
        const float d23 = __fadd_rn(__fsub_rn(rr, __fmul_rn(2.0f, cr3)), cnj[k + 3]);
        if (d20 < bd) { bd = d20; bk = k + 0; }
        if (d21 < bd) { bd = d21; bk = k + 1; }
        if (d22 < bd) { bd = d22; bk = k + 2; }
        if (d23 < bd) { bd = d23; bk = k + 3; }
    }
    return bk;
}
// ===============================================================================

// ---------- Phase A: exact ||c||^2 + split-fp16(-2c) codebook in fragment order ----------
__global__ __launch_bounds__(256) void rvq_prep_kernel(const float* __restrict__ cb,
                                                       uint32_t* __restrict__ apackH,
                                                       uint32_t* __restrict__ apackL,
                                                       float* __restrict__ cn) {
    const int cidx = (int)blockIdx.x * 256 + (int)threadIdx.x;
    if (cidx >= QN * KN) return;
    float row[DN];
    const float4* cp = (const float4*)(cb + (size_t)cidx * DN);
    #pragma unroll
    for (int d4 = 0; d4 < DN / 4; ++d4) {
        const float4 v = cp[d4];
        row[4*d4+0] = v.x; row[4*d4+1] = v.y; row[4*d4+2] = v.z; row[4*d4+3] = v.w;
    }
    cn[cidx] = np_sumsq64(row);                       // frozen exact ||c||^2

    const int j = cidx >> 10, local = cidx & 1023;
    const int c = local >> 5, col = local & 31;
    #pragma unroll
    for (int kk = 0; kk < 4; ++kk) {
        #pragma unroll
        for (int hh = 0; hh < 2; ++hh) {
            AB8 uh, ul;
            #pragma unroll
            for (int e = 0; e < 8; ++e) {
                const float v = -2.0f * row[kk * 16 + hh * 8 + e];   // exact (x2, negate)
                const _Float16 hi = (_Float16)v;
                const float hr = (float)hi;
                const _Float16 lo = (_Float16)__fsub_rn(v, hr);
                uh.h[e] = hi; ul.h[e] = lo;
            }
            const size_t off = (((size_t)(j * 32 + c) * 4 + kk) * 256
                                + (((hh << 5) | col) << 2));
            *(uint4*)(apackH + off) = uh.v;
            *(uint4*)(apackL + off) = ul.v;
        }
    }
}

// med3-based top-3 insert (validated r2-r6).
#define INSV(sv, ixv, B1v, I1v, B2v, I2v, B3v) do {                          \
    const bool lt1 = (sv) < B1v, lt2 = (sv) < B2v;                           \
    B3v = __builtin_amdgcn_fmed3f((sv), B2v, B3v);                           \
    B2v = __builtin_amdgcn_fmed3f((sv), B1v, B2v);                           \
    I2v = lt1 ? I1v : (lt2 ? (ixv) : I2v);                                   \
    B1v = fminf((sv), B1v);                                                  \
    I1v = lt1 ? (ixv) : I1v;                                                 \
} while (0)

__device__ __forceinline__ void splitpack2(float a, float b, uint32_t& H, uint32_t& L) {
    const _Float16 ah = (_Float16)a; const float ar = (float)ah;
    const _Float16 al = (_Float16)__fsub_rn(a, ar);
    const _Float16 bh = (_Float16)b; const float br = (float)bh;
    const _Float16 bl = (_Float16)__fsub_rn(b, br);
    H = (uint32_t)__builtin_bit_cast(uint16_t, ah)
      | ((uint32_t)__builtin_bit_cast(uint16_t, bh) << 16);
    L = (uint32_t)__builtin_bit_cast(uint16_t, al)
      | ((uint32_t)__builtin_bit_cast(uint16_t, bl) << 16);
}

// ---------- Main: reference-exact register residual, split-fp16 MFMA scan ----------
// 1 column group per wave: lanes l, l^32 both own vector (l&31), each holding its own
// 32-dim K-half of x and of the running quantized q (fp32). Per stage: r = fsub(x,q)
// (bit-identical to the reference residual chain), split-fp16 pack -> B fragments.
// Light rescue: full exact rex assembled from registers + 32 partner shuffles, frozen
// rr-tree + cr chains, no gathers. Deep 3-way tie (ultra-rare at this margin): frozen
// gather-rebuild full scan. out_q = q directly (exact chain), no end rebuild.
__global__ __launch_bounds__(256, 3) void rvq_encode_kernel(
    const float* __restrict__ x, const float* __restrict__ cb,
    const uint32_t* __restrict__ apackH, const uint32_t* __restrict__ apackL,
    const float* __restrict__ cnref,
    float* __restrict__ out_enc, float* __restrict__ out_q, int n) {
    const int tid  = (int)threadIdx.x;
    const int lane = tid & 63;
    const int wid  = tid >> 6;
    const int h    = lane >> 5;          // K-half this lane supplies
    const int iv   = (int)blockIdx.x * 128 + wid * 32 + (lane & 31);
    const int ivs  = iv < n ? iv : (n - 1);
    const float* xrow = x + (size_t)ivs * DN;

    // own half of x and q: slot kk*8+e <-> dim kk*16+8h+e
    float x_[32], q_[32];
    #pragma unroll
    for (int kk = 0; kk < 4; ++kk) {
        const float4 a = *(const float4*)(xrow + kk * 16 + 8 * h);
        const float4 b = *(const float4*)(xrow + kk * 16 + 8 * h + 4);
        x_[kk*8+0] = a.x; x_[kk*8+1] = a.y; x_[kk*8+2] = a.z; x_[kk*8+3] = a.w;
        x_[kk*8+4] = b.x; x_[kk*8+5] = b.y; x_[kk*8+6] = b.z; x_[kk*8+7] = b.w;
    }
    #pragma unroll
    for (int t = 0; t < 32; ++t) q_[t] = 0.f;

    int codes[QN] = {0, 0, 0, 0, 0, 0, 0, 0};

    #pragma unroll
    for (int j = 0; j < QN; ++j) {
        // ---- exact residual (reference chain) + split-fp16 pack ----
        uint32_t bhU[16], blU[16];
        {
            float rloc[32];
            #pragma unroll
            for (int t = 0; t < 32; ++t) rloc[t] = __fsub_rn(x_[t], q_[t]);
            #pragma unroll
            for (int kk = 0; kk < 4; ++kk)
                #pragma unroll
                for (int m = 0; m < 4; ++m)
                    splitpack2(rloc[kk*8+2*m], rloc[kk*8+2*m+1],
                               bhU[kk*4+m], blU[kk*4+m]);
        }

        float b1 = FLT_MAX, b2 = FLT_MAX, b3 = FLT_MAX; int i1 = 0, i2 = 0;

        const uint32_t* aH  = apackH + (size_t)j * 32768;
        const uint32_t* aL  = apackL + (size_t)j * 32768;
        const float*    cnj = cnref + (size_t)j * KN;

        #pragma unroll 1
        for (int ch = 0; ch < 32; ++ch) {
            f32x16 acc;
            #pragma unroll
            for (int q = 0; q < 4; ++q) {
                const float4 t = *(const float4*)(cnj + ch * 32 + q * 8 + h * 4);
                acc[4*q+0] = t.x; acc[4*q+1] = t.y; acc[4*q+2] = t.z; acc[4*q+3] = t.w;
            }
            #pragma unroll
            for (int kk = 0; kk < 4; ++kk) {
                AB8 ah_, al_, bh_, bl_;
                ah_.v = *(const uint4*)(aH + (size_t)(ch * 4 + kk) * 256 + lane * 4);
                al_.v = *(const uint4*)(aL + (size_t)(ch * 4 + kk) * 256 + lane * 4);
                bh_.u[0] = bhU[kk*4+0]; bh_.u[1] = bhU[kk*4+1];
                bh_.u[2] = bhU[kk*4+2]; bh_.u[3] = bhU[kk*4+3];
                bl_.u[0] = blU[kk*4+0]; bl_.u[1] = blU[kk*4+1];
                bl_.u[2] = blU[kk*4+2]; bl_.u[3] = blU[kk*4+3];
                acc = __builtin_amdgcn_mfma_f32_32x32x16_f16(ah_.h, bh_.h, acc, 0, 0, 0);
                acc = __builtin_amdgcn_mfma_f32_32x32x16_f16(al_.h, bh_.h, acc, 0, 0, 0);
                acc = __builtin_amdgcn_mfma_f32_32x32x16_f16(ah_.h, bl_.h, acc, 0, 0, 0);
            }
            const int ibase = ch * 32 + 4 * h;
            #pragma unroll
            for (int q = 0; q < 16; ++q) {
                const int ix = ibase + (q & 3) + 8 * (q >> 2);
                const float s = acc[q];
                INSV(s, ix, b1, i1, b2, i2, b3);
            }
        }

        // merge K-half partial lists (lanes l <-> l^32); pb3 can't reach I2 (strict <)
        {
            const float pb1 = __shfl_xor(b1, 32, 64); const int pi1 = __shfl_xor(i1, 32, 64);
            const float pb2 = __shfl_xor(b2, 32, 64); const int pi2 = __shfl_xor(i2, 32, 64);
            const float pb3 = __shfl_xor(b3, 32, 64);
            INSV(pb1, pi1, b1, i1, b2, i2, b3);
            INSV(pb2, pi2, b1, i1, b2, i2, b3);
            INSV(pb3, 0,   b1, i1, b2, i2, b3);
        }

        int chosen = i1;
        if (__builtin_expect(b2 - b1 < MARGIN, 0)) {
            if (__builtin_expect(b3 - b1 < MARGIN, 0)) {
                chosen = full_exact_call(j, xrow, cb, cnj,
                                         codes[0], codes[1], codes[2], codes[3],
                                         codes[4], codes[5], codes[6], codes[7]);
            } else {
                // ---- light exact rescore: rex from registers + partner exchange ----
                float rloc[32], po[32];
                #pragma unroll
                for (int t = 0; t < 32; ++t) rloc[t] = __fsub_rn(x_[t], q_[t]);
                #pragma unroll
                for (int t = 0; t < 32; ++t) po[t] = __shfl_xor(rloc[t], 32, 64);
                float rex[DN];
                #pragma unroll
                for (int kk = 0; kk < 4; ++kk)
                    #pragma unroll
                    for (int e = 0; e < 8; ++e) {
                        rex[kk*16 + e]     = h ? po[kk*8+e]   : rloc[kk*8+e];
                        rex[kk*16 + 8 + e] = h ? rloc[kk*8+e] : po[kk*8+e];
                    }
                const float rr = rr_tree(rex);

                const float* cbj = cb + (size_t)j * KN * DN;
                const float* c0p = cbj + (size_t)i1 * DN;
                const float* c1p = cbj + (size_t)i2 * DN;
                float cr0 = 0.f, cr1 = 0.f;
                #pragma unroll
                for (int d4 = 0; d4 < DN / 4; ++d4) {
                    const float4 a = *(const float4*)(c0p + 4 * d4);
                    const float4 b = *(const float4*)(c1p + 4 * d4);
                    cr0 = __fmaf_rn(rex[4*d4+0], a.x, cr0); cr1 = __fmaf_rn(rex[4*d4+0], b.x, cr1);
                    cr0 = __fmaf_rn(rex[4*d4+1], a.y, cr0); cr1 = __fmaf_rn(rex[4*d4+1], b.y, cr1);
                    cr0 = __fmaf_rn(rex[4*d4+2], a.z, cr0); cr1 = __fmaf_rn(rex[4*d4+2], b.z, cr1);
                    cr0 = __fmaf_rn(rex[4*d4+3], a.w, cr0); cr1 = __fmaf_rn(rex[4*d4+3], b.w, cr1);
                }
                const float d2c0 = __fadd_rn(__fsub_rn(rr, __fmul_rn(2.0f, cr0)), cnj[i1]);
                const float d2c1 = __fadd_rn(__fsub_rn(rr, __fmul_rn(2.0f, cr1)), cnj[i2]);
                float bd = d2c0; int bk = i1;
                if (d2c1 < bd || (d2c1 == bd && i2 < bk)) { bd = d2c1; bk = i2; }
                chosen = bk;
            }
        }
        codes[j] = chosen;   // j static (unrolled stage loop)

        // ---- q update: reference-exact fadd chain, own half only ----
        {
            const float* cw = cb + ((size_t)j * KN + chosen) * DN;
            #pragma unroll
            for (int kk = 0; kk < 4; ++kk) {
                const float4 a = *(const float4*)(cw + kk * 16 + 8 * h);
                const float4 b = *(const float4*)(cw + kk * 16 + 8 * h + 4);
                q_[kk*8+0] = __fadd_rn(q_[kk*8+0], a.x);
                q_[kk*8+1] = __fadd_rn(q_[kk*8+1], a.y);
                q_[kk*8+2] = __fadd_rn(q_[kk*8+2], a.z);
                q_[kk*8+3] = __fadd_rn(q_[kk*8+3], a.w);
                q_[kk*8+4] = __fadd_rn(q_[kk*8+4], b.x);
                q_[kk*8+5] = __fadd_rn(q_[kk*8+5], b.y);
                q_[kk*8+6] = __fadd_rn(q_[kk*8+6], b.z);
                q_[kk*8+7] = __fadd_rn(q_[kk*8+7], b.w);
            }
        }
    }

    if (iv < n) {
        if (h == 0) {
            float4 e0, e1;
            e0.x = (float)codes[0]; e0.y = (float)codes[1];
            e0.z = (float)codes[2]; e0.w = (float)codes[3];
            e1.x = (float)codes[4]; e1.y = (float)codes[5];
            e1.z = (float)codes[6]; e1.w = (float)codes[7];
            *(float4*)(out_enc + (size_t)iv * QN)     = e0;
            *(float4*)(out_enc + (size_t)iv * QN + 4) = e1;
        }
        // out_q = q (reference-exact chain); each half writes its own float4 blocks
        float4* qo = (float4*)(out_q + (size_t)iv * DN);
        #pragma unroll
        for (int kk = 0; kk < 4; ++kk) {
            float4 o0, o1;
            o0.x = q_[kk*8+0]; o0.y = q_[kk*8+1]; o0.z = q_[kk*8+2]; o0.w = q_[kk*8+3];
            o1.x = q_[kk*8+4]; o1.y = q_[kk*8+5]; o1.z = q_[kk*8+6]; o1.w = q_[kk*8+7];
            qo[kk*4 + 2*h]     = o0;
            qo[kk*4 + 2*h + 1] = o1;
        }
    }
}

extern "C" void kernel_launch(void* const* d_in, const int* in_sizes, int n_in,
                              void* d_out, int out_size, void* d_ws, size_t ws_size,
                              hipStream_t stream) {
    const float* x   = (const float*)d_in[0];
    const float* cbp = (const float*)d_in[1];
    const int n = in_sizes[0] / DN;

    float* out_enc = (float*)d_out;                   // [N, Q]
    float* out_q   = (float*)d_out + (size_t)n * QN;  // [N, D]

    // workspace: 1 MiB apackH + 1 MiB apackL (fragment-order fp16) + 32 KiB ||c||^2
    uint32_t* apackH = (uint32_t*)d_ws;
    uint32_t* apackL = (uint32_t*)((char*)d_ws + (size_t)QN * KN * DN * 2);
    float*    cn     = (float*)((char*)d_ws + (size_t)QN * KN * DN * 4);

    rvq_prep_kernel<<<dim3((QN * KN + 255) / 256), dim3(256), 0, stream>>>(
        cbp, apackH, apackL, cn);
    rvq_encode_kernel<<<dim3((n + 127) / 128), dim3(256), 0, stream>>>(
        x, cbp, apackH, apackL, cn, out_enc, out_q, n);
}